// Round 5
// baseline (128.737 us; speedup 1.0000x reference)
//
#include <hip/hip_runtime.h>

#define S 512
#define H 128
#define NROW 4096   // B*S
#define TI 4

// ---------------- kernel 0: W1 [128][256] -> w1T [256][128] ----------------
__global__ __launch_bounds__(256) void w1t_kernel(const float* __restrict__ W1,
                                                  float* __restrict__ w1T) {
  __shared__ float t[32][33];
  const int d0 = (blockIdx.x & 7) * 32;   // col tile (d in 0..255)
  const int h0 = (blockIdx.x >> 3) * 32;  // row tile (h in 0..127)
  const int tx = threadIdx.x & 31, ty = threadIdx.x >> 5;  // ty 0..7
  #pragma unroll
  for (int r = 0; r < 4; r++)
    t[ty + r * 8][tx] = W1[(h0 + ty + r * 8) * 256 + d0 + tx];
  __syncthreads();
  #pragma unroll
  for (int r = 0; r < 4; r++)
    w1T[(size_t)(d0 + ty + r * 8) * H + h0 + tx] = t[tx][ty + r * 8];
}

// ---------------- kernel 1: projection (2 rows/wave, 8 waves/SIMD) ----------------
// qp[row][h]  = sum_d query[row][d]*w1T[d][h] + b1[h]
// kp2[h/16][row][h%16] = sum_d key[row][d]*w1T[128+d][h]
// qw[row] = 0.5*sum_h qp[row][h]*W2[h] + b2;  kw[row] = 0.5*sum_h kp[row][h]*W2[h]
__global__ __launch_bounds__(256, 8) void proj_kernel(
    const float* __restrict__ query, const float* __restrict__ key,
    const float* __restrict__ w1T, const float* __restrict__ b1,
    const float* __restrict__ W2, const float* __restrict__ b2,
    float* __restrict__ qp, float* __restrict__ kp2,
    float* __restrict__ qw, float* __restrict__ kw)
{
  const int bid = blockIdx.x;        // 0..1023
  const bool isq = bid < 512;
  const float* __restrict__ src = isq ? query : key;
  const int rbase = (isq ? bid : bid - 512) * 8;
  const int doff = isq ? 0 : 128;
  const int tid = threadIdx.x;
  const int w = __builtin_amdgcn_readfirstlane(tid >> 6);
  const int lane = tid & 63;
  const int r0w = rbase + w * 2;     // this wave's 2 rows

  float acc[2][2];
  float2 bv = make_float2(0.f, 0.f);
  if (isq) bv = *(const float2*)(b1 + 2 * lane);
  acc[0][0] = bv.x; acc[0][1] = bv.y;
  acc[1][0] = bv.x; acc[1][1] = bv.y;

  #pragma unroll 1
  for (int dc = 0; dc < 128; dc += 16) {
    float qs[2][16];                 // wave-uniform -> SGPR batch
    #pragma unroll
    for (int r = 0; r < 2; r++) {
      const float* sp = src + (size_t)(r0w + r) * H + dc;
      #pragma unroll
      for (int u = 0; u < 16; u++) qs[r][u] = sp[u];
    }
    float2 wv[16];
    #pragma unroll
    for (int dd = 0; dd < 16; dd++)
      wv[dd] = *(const float2*)(w1T + (size_t)(doff + dc + dd) * H + 2 * lane);
    #pragma unroll
    for (int dd = 0; dd < 16; dd++) {
      acc[0][0] = __builtin_fmaf(qs[0][dd], wv[dd].x, acc[0][0]);
      acc[0][1] = __builtin_fmaf(qs[0][dd], wv[dd].y, acc[0][1]);
      acc[1][0] = __builtin_fmaf(qs[1][dd], wv[dd].x, acc[1][0]);
      acc[1][1] = __builtin_fmaf(qs[1][dd], wv[dd].y, acc[1][1]);
    }
  }

  // qw / kw: wave butterfly over h (lane owns h = 2*lane, 2*lane+1)
  const float2 w2p = *(const float2*)(W2 + 2 * lane);
  const float b2v = b2[0];
  #pragma unroll
  for (int r = 0; r < 2; r++) {
    float t = acc[r][0] * w2p.x + acc[r][1] * w2p.y;
    #pragma unroll
    for (int m = 1; m <= 32; m <<= 1) t += __shfl_xor(t, m, 64);
    if (lane == 0) {
      if (isq) qw[r0w + r] = 0.5f * t + b2v;
      else     kw[r0w + r] = 0.5f * t;
    }
  }

  if (isq) {
    #pragma unroll
    for (int r = 0; r < 2; r++)
      *(float2*)(qp + (size_t)(r0w + r) * H + 2 * lane) =
          make_float2(acc[r][0], acc[r][1]);
  } else {
    // kp2[hblk][row][u]: hblk = (2*lane)/16 = lane>>3, u = (2*lane)%16
    #pragma unroll
    for (int r = 0; r < 2; r++)
      *(float2*)(kp2 + ((size_t)(lane >> 3) * NROW + (r0w + r)) * 16 +
                 (lane & 7) * 2) = make_float2(acc[r][0], acc[r][1]);
  }
}

// ---------------- kernel 2: fused scores + exp + AV + output ----------------
// grid: 1024 i-tiles (TI=4); 512 threads = 8 waves; wave w owns j-block w*64.
// Phase 1: 16-h passes, k+W2 VGPR-resident (32 VGPRs), q streamed as 2-row
// SGPR batches. 8 waves/SIMD for latency hiding; VGPR capped at 64.
__global__ __launch_bounds__(512, 8) void attn_kernel(
    const float* __restrict__ qp, const float* __restrict__ kp2,
    const float* __restrict__ qw, const float* __restrict__ kw,
    const float* __restrict__ value, const int* __restrict__ q_mask,
    const int* __restrict__ k_mask, const float* __restrict__ W2,
    float* __restrict__ out)
{
  __shared__ float aT[8][64][4];      // a, per wave [j][i]
  __shared__ float numw[8][TI][132];  // per-wave num partials
  __shared__ float denw[8][TI];

  const int it = blockIdx.x;          // 0..1023
  const int r0 = it * TI;
  const int b  = r0 >> 9;
  const int tid = threadIdx.x;
  const int w = __builtin_amdgcn_readfirstlane(tid >> 6);
  const int lane = tid & 63;
  const int jg = (b << 9) + (w << 6) + lane;   // global key row
  const int km = k_mask[jg];
  const float kwj = kw[jg];

  // ---- phase 1: s[i] = sum_h |q+k| * W2  (x0.5 folded at the end) ----
  float s[TI];
  #pragma unroll
  for (int i = 0; i < TI; i++) s[i] = 0.f;

  #pragma unroll 1
  for (int hb = 0; hb < 8; hb++) {    // 16-h window
    float kr[16];
    {
      const float* __restrict__ kk = kp2 + (((size_t)hb * NROW + jg) << 4);
      #pragma unroll
      for (int u = 0; u < 4; u++) *(float4*)&kr[u * 4] = ((const float4*)kk)[u];
    }
    float w2r[16];
    #pragma unroll
    for (int u = 0; u < 16; u++) w2r[u] = W2[hb * 16 + u];   // uniform -> SGPR

    #pragma unroll 1
    for (int ip = 0; ip < TI; ip += 2) {
      float q0[16], q1[16];           // uniform -> SGPR batches
      {
        const float* __restrict__ qa = qp + (size_t)(r0 + ip) * H + hb * 16;
        #pragma unroll
        for (int u = 0; u < 16; u++) { q0[u] = qa[u]; q1[u] = qa[H + u]; }
      }
      float s0 = s[ip], s1 = s[ip + 1];
      #pragma unroll
      for (int u = 0; u < 16; u++) {
        const float t0 = q0[u] + kr[u];
        const float t1 = q1[u] + kr[u];
        s0 = __builtin_fmaf(fabsf(t0), w2r[u], s0);
        s1 = __builtin_fmaf(fabsf(t1), w2r[u], s1);
      }
      s[ip] = s0; s[ip + 1] = s1;
    }
  }

  // ---- mask + exp ----
  float a[TI];
  #pragma unroll
  for (int i = 0; i < TI; i++) {
    const float qws = qw[r0 + i];     // uniform (b2 folded in)
    const int qm = q_mask[r0 + i];    // uniform
    a[i] = (km > 0 && qm > 0) ? __expf(__builtin_fmaf(0.5f, s[i], qws + kwj))
                              : 0.f;
  }
  *(float4*)&aT[w][lane][0] = make_float4(a[0], a[1], a[2], a[3]);
  // no barrier: aT[w] is wave-private

  // ---- phase 2: num[i][h] += a[i][j]*v[j][h]; den folded in ----
  const int lj = lane >> 5, lh = lane & 31;
  float nr[TI][4];
  float dden[TI];
  #pragma unroll
  for (int i = 0; i < TI; i++) {
    nr[i][0] = 0.f; nr[i][1] = 0.f; nr[i][2] = 0.f; nr[i][3] = 0.f;
    dden[i] = 0.f;
  }
  const float* __restrict__ vbase =
      value + ((size_t)b * S + (w << 6)) * H;

  #pragma unroll 1
  for (int js = 0; js < 32; js++) {
    const int j = js * 2 + lj;
    const float4 vv = *(const float4*)(vbase + (size_t)j * H + lh * 4);
    const float4 a4 = *(const float4*)&aT[w][j][0];
    const float av[4] = {a4.x, a4.y, a4.z, a4.w};
    #pragma unroll
    for (int i = 0; i < TI; i++) {
      nr[i][0] = __builtin_fmaf(av[i], vv.x, nr[i][0]);
      nr[i][1] = __builtin_fmaf(av[i], vv.y, nr[i][1]);
      nr[i][2] = __builtin_fmaf(av[i], vv.z, nr[i][2]);
      nr[i][3] = __builtin_fmaf(av[i], vv.w, nr[i][3]);
      dden[i] += av[i];
    }
  }
  #pragma unroll
  for (int i = 0; i < TI; i++) {
    #pragma unroll
    for (int k = 0; k < 4; k++) nr[i][k] += __shfl_xor(nr[i][k], 32, 64);
    dden[i] += __shfl_xor(dden[i], 32, 64);
  }
  if (lj == 0) {
    #pragma unroll
    for (int i = 0; i < TI; i++)
      *(float4*)&numw[w][i][lh * 4] =
          make_float4(nr[i][0], nr[i][1], nr[i][2], nr[i][3]);
    if (lane == 0) {
      #pragma unroll
      for (int i = 0; i < TI; i++) denw[w][i] = dden[i];
    }
  }
  __syncthreads();

  // ---- final: sum 8 wave-partials, divide, store ----
  {
    const int i = w & 3, half = w >> 2;      // wave -> (row, h-half)
    float acc = 0.f, den = 0.f;
    #pragma unroll
    for (int ww = 0; ww < 8; ww++) {
      acc += numw[ww][i][half * 64 + lane];
      den += denw[ww][i];
    }
    const float inv = 1.f / fmaxf(den, 2e-15f);
    out[(size_t)(r0 + i) * H + half * 64 + lane] = acc * inv;
  }
}

extern "C" void kernel_launch(void* const* d_in, const int* in_sizes, int n_in,
                              void* d_out, int out_size, void* d_ws, size_t ws_size,
                              hipStream_t stream)
{
  (void)in_sizes; (void)n_in; (void)out_size; (void)ws_size;
  const float* query  = (const float*)d_in[0];
  const float* key    = (const float*)d_in[1];
  const float* value  = (const float*)d_in[2];
  const int*   q_mask = (const int*)d_in[3];
  const int*   k_mask = (const int*)d_in[4];
  const float* W1     = (const float*)d_in[5];
  const float* b1     = (const float*)d_in[6];
  const float* W2     = (const float*)d_in[7];
  const float* b2     = (const float*)d_in[8];
  float* out = (float*)d_out;

  float* ws   = (float*)d_ws;
  float* w1T  = ws;                                  // [256][128]
  float* qp   = w1T + 256 * H;                       // [4096][128]
  float* kp2  = qp + (size_t)NROW * H;               // [8][4096][16]
  float* qw   = kp2 + (size_t)NROW * H;              // [4096]
  float* kw   = qw + NROW;                           // [4096]

  w1t_kernel<<<32, 256, 0, stream>>>(W1, w1T);
  proj_kernel<<<1024, 256, 0, stream>>>(query, key, w1T, b1, W2, b2,
                                        qp, kp2, qw, kw);
  attn_kernel<<<1024, 512, 0, stream>>>(qp, kp2, qw, kw, value, q_mask,
                                        k_mask, W2, out);
}

// Round 6
// 128.202 us; speedup vs baseline: 1.0042x; 1.0042x over previous
//
#include <hip/hip_runtime.h>

#define S 512
#define H 128
#define NROW 4096   // B*S
#define TI 4

// kp3 layout: [hb 0..7][jb 0..63][hq 0..3][jl 0..63][hm 0..3]
//   element (j, h): hb=h>>4, hq=(h>>2)&3, hm=h&3, jb=j>>6, jl=j&63
//   -> for fixed (hb,jb,hq), 64 lanes (jl) read contiguous float4s = 1KB.

// ---------------- kernel 0: W1 [128][256] -> w1T [256][128] ----------------
__global__ __launch_bounds__(256) void w1t_kernel(const float* __restrict__ W1,
                                                  float* __restrict__ w1T) {
  __shared__ float t[32][33];
  const int d0 = (blockIdx.x & 7) * 32;   // col tile (d in 0..255)
  const int h0 = (blockIdx.x >> 3) * 32;  // row tile (h in 0..127)
  const int tx = threadIdx.x & 31, ty = threadIdx.x >> 5;  // ty 0..7
  #pragma unroll
  for (int r = 0; r < 4; r++)
    t[ty + r * 8][tx] = W1[(h0 + ty + r * 8) * 256 + d0 + tx];
  __syncthreads();
  #pragma unroll
  for (int r = 0; r < 4; r++)
    w1T[(size_t)(d0 + ty + r * 8) * H + h0 + tx] = t[tx][ty + r * 8];
}

// ---------------- kernel 1: projection (8 rows/wave) ----------------
// qp[row][h]  = sum_d query[row][d]*w1T[d][h] + b1[h]
// kp3[...]    = sum_d key[row][d]*w1T[128+d][h]   (scatter to kp3 layout)
// qw[row] = 0.5*sum_h qp[row][h]*W2[h] + b2;  kw[row] = 0.5*sum_h kp[row][h]*W2[h]
__global__ __launch_bounds__(256) void proj_kernel(
    const float* __restrict__ query, const float* __restrict__ key,
    const float* __restrict__ w1T, const float* __restrict__ b1,
    const float* __restrict__ W2, const float* __restrict__ b2,
    float* __restrict__ qp, float* __restrict__ kp3,
    float* __restrict__ qw, float* __restrict__ kw)
{
  const int bid = blockIdx.x;        // 0..255
  const bool isq = bid < 128;
  const float* __restrict__ src = isq ? query : key;
  const int rbase = (isq ? bid : bid - 128) * 32;
  const int doff = isq ? 0 : 128;
  const int tid = threadIdx.x;
  const int w = __builtin_amdgcn_readfirstlane(tid >> 6);
  const int lane = tid & 63;
  const int r0w = rbase + w * 8;     // this wave's 8 rows

  float acc[8][2];
  float2 bv = make_float2(0.f, 0.f);
  if (isq) bv = *(const float2*)(b1 + 2 * lane);
  #pragma unroll
  for (int r = 0; r < 8; r++) { acc[r][0] = bv.x; acc[r][1] = bv.y; }

  #pragma unroll 1
  for (int dc = 0; dc < 128; dc += 8) {
    float qs[8][8];                  // wave-uniform -> SGPR (s_load_dwordx8)
    #pragma unroll
    for (int r = 0; r < 8; r++) {
      const float* sp = src + (size_t)(r0w + r) * H + dc;
      #pragma unroll
      for (int u = 0; u < 8; u++) qs[r][u] = sp[u];
    }
    float2 wv[8];
    #pragma unroll
    for (int dd = 0; dd < 8; dd++)
      wv[dd] = *(const float2*)(w1T + (size_t)(doff + dc + dd) * H + 2 * lane);
    #pragma unroll
    for (int dd = 0; dd < 8; dd++) {
      #pragma unroll
      for (int r = 0; r < 8; r++) {
        acc[r][0] = __builtin_fmaf(qs[r][dd], wv[dd].x, acc[r][0]);
        acc[r][1] = __builtin_fmaf(qs[r][dd], wv[dd].y, acc[r][1]);
      }
    }
  }

  // qw / kw: wave butterfly over h (lane owns h = 2*lane, 2*lane+1)
  const float2 w2p = *(const float2*)(W2 + 2 * lane);
  const float b2v = b2[0];
  #pragma unroll
  for (int r = 0; r < 8; r++) {
    float t = acc[r][0] * w2p.x + acc[r][1] * w2p.y;
    #pragma unroll
    for (int m = 1; m <= 32; m <<= 1) t += __shfl_xor(t, m, 64);
    if (lane == 0) {
      if (isq) qw[r0w + r] = 0.5f * t + b2v;
      else     kw[r0w + r] = 0.5f * t;
    }
  }

  if (isq) {
    #pragma unroll
    for (int r = 0; r < 8; r++)
      *(float2*)(qp + (size_t)(r0w + r) * H + 2 * lane) =
          make_float2(acc[r][0], acc[r][1]);
  } else {
    // scatter to kp3: h0 = 2*lane -> hb=lane>>3, hq=(lane>>1)&3, hm=(lane&1)*2
    const int hb = lane >> 3, hq = (lane >> 1) & 3, hm = (lane & 1) * 2;
    #pragma unroll
    for (int r = 0; r < 8; r++) {
      const int j = r0w + r;
      float* dst = kp3 +
          ((((size_t)hb * 64 + (j >> 6)) * 4 + hq) * 64 + (j & 63)) * 4 + hm;
      *(float2*)dst = make_float2(acc[r][0], acc[r][1]);
    }
  }
}

// ---------------- kernel 2: fused scores + exp + AV + output ----------------
// grid: 1024 i-tiles (TI=4); 512 threads = 8 waves; wave w owns j-block w*64.
// Phase 1: k loads fully lane-coalesced via kp3 layout; q streamed as 2-row
// SGPR batches; W2 in SGPRs. 8 waves/SIMD.
__global__ __launch_bounds__(512, 8) void attn_kernel(
    const float* __restrict__ qp, const float* __restrict__ kp3,
    const float* __restrict__ qw, const float* __restrict__ kw,
    const float* __restrict__ value, const int* __restrict__ q_mask,
    const int* __restrict__ k_mask, const float* __restrict__ W2,
    float* __restrict__ out)
{
  __shared__ float aT[8][64][4];      // a, per wave [j][i]
  __shared__ float numw[8][TI][132];  // per-wave num partials
  __shared__ float denw[8][TI];

  const int it = blockIdx.x;          // 0..1023
  const int r0 = it * TI;
  const int b  = r0 >> 9;
  const int tid = threadIdx.x;
  const int w = __builtin_amdgcn_readfirstlane(tid >> 6);
  const int lane = tid & 63;
  const int jg = (b << 9) + (w << 6) + lane;   // global key row
  const int jb = (b << 3) + w;                 // global j-block (jg>>6)
  const int km = k_mask[jg];
  const float kwj = kw[jg];

  // ---- phase 1: s[i] = sum_h |q+k| * W2  (x0.5 folded at the end) ----
  float s[TI];
  #pragma unroll
  for (int i = 0; i < TI; i++) s[i] = 0.f;

  #pragma unroll 1
  for (int hb = 0; hb < 8; hb++) {    // 16-h window
    // coalesced: 64 lanes read contiguous 1KB per hq
    const float* __restrict__ kk =
        kp3 + ((size_t)(hb * 64 + jb)) * 1024 + lane * 4;
    float kr[16];
    *(float4*)&kr[0]  = *(const float4*)(kk);
    *(float4*)&kr[4]  = *(const float4*)(kk + 256);
    *(float4*)&kr[8]  = *(const float4*)(kk + 512);
    *(float4*)&kr[12] = *(const float4*)(kk + 768);
    float w2r[16];
    #pragma unroll
    for (int u = 0; u < 16; u++) w2r[u] = W2[hb * 16 + u];   // uniform -> SGPR

    #pragma unroll 1
    for (int ip = 0; ip < TI; ip += 2) {
      float q0[16], q1[16];           // uniform -> SGPR batches
      {
        const float* __restrict__ qa = qp + (size_t)(r0 + ip) * H + hb * 16;
        #pragma unroll
        for (int u = 0; u < 16; u++) { q0[u] = qa[u]; q1[u] = qa[H + u]; }
      }
      float s0 = s[ip], s1 = s[ip + 1];
      #pragma unroll
      for (int u = 0; u < 16; u++) {
        const float t0 = q0[u] + kr[u];
        const float t1 = q1[u] + kr[u];
        s0 = __builtin_fmaf(fabsf(t0), w2r[u], s0);
        s1 = __builtin_fmaf(fabsf(t1), w2r[u], s1);
      }
      s[ip] = s0; s[ip + 1] = s1;
    }
  }

  // ---- mask + exp ----
  float a[TI];
  #pragma unroll
  for (int i = 0; i < TI; i++) {
    const float qws = qw[r0 + i];     // uniform (b2 folded in)
    const int qm = q_mask[r0 + i];    // uniform
    a[i] = (km > 0 && qm > 0) ? __expf(__builtin_fmaf(0.5f, s[i], qws + kwj))
                              : 0.f;
  }
  *(float4*)&aT[w][lane][0] = make_float4(a[0], a[1], a[2], a[3]);
  // no barrier: aT[w] is wave-private

  // ---- phase 2: num[i][h] += a[i][j]*v[j][h]; den folded in ----
  const int lj = lane >> 5, lh = lane & 31;
  float nr[TI][4];
  float dden[TI];
  #pragma unroll
  for (int i = 0; i < TI; i++) {
    nr[i][0] = 0.f; nr[i][1] = 0.f; nr[i][2] = 0.f; nr[i][3] = 0.f;
    dden[i] = 0.f;
  }
  const float* __restrict__ vbase =
      value + ((size_t)b * S + (w << 6)) * H;

  #pragma unroll 1
  for (int js = 0; js < 32; js++) {
    const int j = js * 2 + lj;
    const float4 vv = *(const float4*)(vbase + (size_t)j * H + lh * 4);
    const float4 a4 = *(const float4*)&aT[w][j][0];
    const float av[4] = {a4.x, a4.y, a4.z, a4.w};
    #pragma unroll
    for (int i = 0; i < TI; i++) {
      nr[i][0] = __builtin_fmaf(av[i], vv.x, nr[i][0]);
      nr[i][1] = __builtin_fmaf(av[i], vv.y, nr[i][1]);
      nr[i][2] = __builtin_fmaf(av[i], vv.z, nr[i][2]);
      nr[i][3] = __builtin_fmaf(av[i], vv.w, nr[i][3]);
      dden[i] += av[i];
    }
  }
  #pragma unroll
  for (int i = 0; i < TI; i++) {
    #pragma unroll
    for (int k = 0; k < 4; k++) nr[i][k] += __shfl_xor(nr[i][k], 32, 64);
    dden[i] += __shfl_xor(dden[i], 32, 64);
  }
  if (lj == 0) {
    #pragma unroll
    for (int i = 0; i < TI; i++)
      *(float4*)&numw[w][i][lh * 4] =
          make_float4(nr[i][0], nr[i][1], nr[i][2], nr[i][3]);
    if (lane == 0) {
      #pragma unroll
      for (int i = 0; i < TI; i++) denw[w][i] = dden[i];
    }
  }
  __syncthreads();

  // ---- final: sum 8 wave-partials, divide, store ----
  {
    const int i = w & 3, half = w >> 2;      // wave -> (row, h-half)
    float acc = 0.f, den = 0.f;
    #pragma unroll
    for (int ww = 0; ww < 8; ww++) {
      acc += numw[ww][i][half * 64 + lane];
      den += denw[ww][i];
    }
    const float inv = 1.f / fmaxf(den, 2e-15f);
    out[(size_t)(r0 + i) * H + half * 64 + lane] = acc * inv;
  }
}

extern "C" void kernel_launch(void* const* d_in, const int* in_sizes, int n_in,
                              void* d_out, int out_size, void* d_ws, size_t ws_size,
                              hipStream_t stream)
{
  (void)in_sizes; (void)n_in; (void)out_size; (void)ws_size;
  const float* query  = (const float*)d_in[0];
  const float* key    = (const float*)d_in[1];
  const float* value  = (const float*)d_in[2];
  const int*   q_mask = (const int*)d_in[3];
  const int*   k_mask = (const int*)d_in[4];
  const float* W1     = (const float*)d_in[5];
  const float* b1     = (const float*)d_in[6];
  const float* W2     = (const float*)d_in[7];
  const float* b2     = (const float*)d_in[8];
  float* out = (float*)d_out;

  float* ws   = (float*)d_ws;
  float* w1T  = ws;                                  // [256][128]
  float* qp   = w1T + 256 * H;                       // [4096][128]
  float* kp3  = qp + (size_t)NROW * H;               // [8][64][4][64][4]
  float* qw   = kp3 + (size_t)NROW * H;              // [4096]
  float* kw   = qw + NROW;                           // [4096]

  w1t_kernel<<<32, 256, 0, stream>>>(W1, w1T);
  proj_kernel<<<256, 256, 0, stream>>>(query, key, w1T, b1, W2, b2,
                                       qp, kp3, qw, kw);
  attn_kernel<<<1024, 512, 0, stream>>>(qp, kp3, qw, kw, value, q_mask,
                                        k_mask, W2, out);
}